// Round 10
// baseline (259.432 us; speedup 1.0000x reference)
//
#include <hip/hip_runtime.h>
#include <math.h>

// Problem constants (fixed by reference setup_inputs)
constexpr int B   = 128;
constexpr int T   = 300;
constexpr int D   = 1024;   // video dim
constexpr int DA  = 128;    // audio dim
constexpr int TS  = T - 1;  // 299 similarities per batch
constexpr int K   = 32;
constexpr int KP1 = K + 1;

constexpr int SEG     = 10;    // sims per wave — arrays fit in VGPRs (no spill)
constexpr int BPB     = 8;     // producer blocks per batch (8*4 waves*10 = 320 >= 299)
constexpr int SIMS_LD = 320;   // padded stride (floats): 1280 B — no cache line
                               // shared between batches (cross-XCD safety)
#define EPS_D 1e-5

__device__ __forceinline__ void loadrow(const float* __restrict__ row, int lane, float r[16]) {
    const float4* f = (const float4*)row;
#pragma unroll
    for (int j = 0; j < 4; ++j) {
        float4 x = f[lane + 64 * j];
        r[4 * j + 0] = x.x; r[4 * j + 1] = x.y;
        r[4 * j + 2] = x.z; r[4 * j + 3] = x.w;
    }
}

// Single-dispatch producer/consumer:
//   1024 blocks x 256 thr; block = (batch b, octant o). 4 waves compute
//   4x10 sims (f64 accumulation — absmax 0.0 in R0/R1/R4/R6/R8) into padded
//   global sims. Last finishing block of each batch (device-scope atomic
//   counter) becomes the consumer: LDS rank-select + gather. No grid.sync,
//   no spin. SEG=10 keeps accumulator arrays in VGPRs (R8's SEG=19 spilled
//   to scratch: VGPR=84 vs ~110 needed -> 165 us).
__global__ __launch_bounds__(256) void fusedpc_kernel(const float* __restrict__ video,
                                                      const float* __restrict__ audio,
                                                      float* sims, int* cnt,
                                                      float* __restrict__ out) {
    int b    = blockIdx.x >> 3;
    int o    = blockIdx.x & 7;
    int tid  = threadIdx.x;
    int w    = tid >> 6;
    int lane = tid & 63;

    const float* vb = video + (size_t)b * T * D;

    // ---- producer: sims for segment g = o*4+w, s in [s0, s0+10) ----
    {
        int g  = (o << 2) | w;          // 0..31
        int s0 = g * SEG;

        float p[16];
        loadrow(vb + (size_t)min(s0, TS) * D, lane, p);
        double pn0 = 0.0;
#pragma unroll
        for (int j = 0; j < 16; ++j) pn0 += (double)p[j] * (double)p[j];

        double cnA[SEG], dtA[SEG];
#pragma unroll
        for (int i = 0; i < SEG; ++i) {
            int s = s0 + i;
            int rowIdx = min(s + 1, TS);   // clamp tail loads
            float c[16];
            loadrow(vb + (size_t)rowIdx * D, lane, c);
            double cn = 0.0, dt = 0.0;
#pragma unroll
            for (int j = 0; j < 16; ++j) {
                cn += (double)c[j] * (double)c[j];
                dt += (double)c[j] * (double)p[j];
            }
            cnA[i] = cn; dtA[i] = dt;
#pragma unroll
            for (int j = 0; j < 16; ++j) p[j] = c[j];
        }
#pragma unroll
        for (int off = 32; off; off >>= 1) {
            pn0 += __shfl_xor(pn0, off);
#pragma unroll
            for (int i = 0; i < SEG; ++i) {
                cnA[i] += __shfl_xor(cnA[i], off);
                dtA[i] += __shfl_xor(dtA[i], off);
            }
        }
        if (lane == 0) {
            double nprev = sqrt(pn0) + EPS_D;
#pragma unroll
            for (int i = 0; i < SEG; ++i) {
                int s = s0 + i;
                double ncur = sqrt(cnA[i]) + EPS_D;
                if (s < TS) sims[b * SIMS_LD + s] = (float)(fabs(dtA[i]) / (nprev * ncur));
                nprev = ncur;
            }
        }
    }

    // ---- handoff: release writes, count octants; last block consumes ----
    __threadfence();                       // make this thread's sims writes device-visible
    __syncthreads();
    __shared__ int isLast;
    if (tid == 0) {
        int old = atomicAdd(&cnt[b], 1);   // device-scope
        isLast = (old == BPB - 1);
    }
    __syncthreads();
    if (!isLast) return;
    __threadfence();                       // acquire: reads below ordered after atomic

    // ---- consumer: rank-select in LDS ----
    __shared__ float S[TS];
    __shared__ int   idxs[KP1];
    for (int e = tid; e < TS; e += 256) S[e] = sims[b * SIMS_LD + e];
    if (tid == 0) idxs[0] = 0;
    __syncthreads();

    for (int e = tid; e < TS; e += 256) {
        float val = S[e];
        int rank = 0;
#pragma unroll 4
        for (int j = 0; j < TS; ++j) {
            float sj = S[j];
            rank += (sj < val) || (sj == val && j < e);
        }
        if (rank < K) idxs[rank + 1] = e + 1;   // ranks unique => no conflicts
    }
    __syncthreads();

    // ---- consumer: gather 33 video + audio rows ----
#pragma unroll 4
    for (int k = 0; k < KP1; ++k) {
        int t = idxs[k];
        const float4* vs = (const float4*)(vb + (size_t)t * D);
        float4*       vd = (float4*)(out + ((size_t)b * KP1 + k) * D);
        vd[tid] = vs[tid];                  // 256 float4 = full row
    }
    const float* ab   = audio + (size_t)b * T * DA;
    float*       outA = out + (size_t)B * KP1 * D + (size_t)b * KP1 * DA;
    for (int a = tid; a < KP1 * (DA / 4); a += 256) {
        int k = a >> 5, off = a & 31;
        int t = idxs[k];
        ((float4*)(outA + (size_t)k * DA))[off] =
            ((const float4*)(ab + (size_t)t * DA))[off];
    }
}

extern "C" void kernel_launch(void* const* d_in, const int* in_sizes, int n_in,
                              void* d_out, int out_size, void* d_ws, size_t ws_size,
                              hipStream_t stream) {
    const float* video = (const float*)d_in[0];
    const float* audio = (const float*)d_in[1];
    float* out  = (float*)d_out;

    float* sims = (float*)d_ws;                                  // 128*320*4 = 160 KB
    int*   cnt  = (int*)((char*)d_ws + (size_t)B * SIMS_LD * sizeof(float));

    // zero the per-batch octant counters (capture-safe async memset)
    hipMemsetAsync(cnt, 0, B * sizeof(int), stream);

    fusedpc_kernel<<<B * BPB, 256, 0, stream>>>(video, audio, sims, cnt, out);
}

// Round 12
// 52.926 us; speedup vs baseline: 4.9018x; 4.9018x over previous
//
#include <hip/hip_runtime.h>
#include <math.h>

// Problem constants (fixed by reference setup_inputs)
constexpr int B   = 128;
constexpr int T   = 300;
constexpr int D   = 1024;   // video dim
constexpr int DA  = 128;    // audio dim
constexpr int TS  = T - 1;  // 299 similarities per batch
constexpr int K   = 32;
constexpr int KP1 = K + 1;

constexpr int SEGW = 19;    // sims per wave: 16 waves * 19 = 304 >= 299

#define EPS_D 1e-5

__device__ __forceinline__ void loadrow(const float* __restrict__ row, int lane, float r[16]) {
    const float4* f = (const float4*)row;
#pragma unroll
    for (int j = 0; j < 4; ++j) {
        float4 x = f[lane + 64 * j];
        r[4 * j + 0] = x.x; r[4 * j + 1] = x.y;
        r[4 * j + 2] = x.z; r[4 * j + 3] = x.w;
    }
}

// One block per batch, 1024 threads, ONE dispatch total.
// Phase A: 16 waves x 19 sims, f64 accumulation with IMMEDIATE per-sim
//   butterfly (R0's proven order — absmax 0.0; no accumulator arrays, so
//   no scratch spill, unlike R5's VGPR=64/85MB-spill variant).
// Phase B: LDS rank-select (rank<K == top_k(-sim) stable winners).
// Phase C: gather 33 video+audio rows (L2-warm from phase A).
// No atomics, no fences, no grid.sync, no workspace.
__global__ __launch_bounds__(1024) void fused1_kernel(const float* __restrict__ video,
                                                      const float* __restrict__ audio,
                                                      float* __restrict__ out) {
    __shared__ float S[TS];
    __shared__ int   idxs[KP1];

    int b    = blockIdx.x;
    int tid  = threadIdx.x;
    int w    = tid >> 6;
    int lane = tid & 63;

    const float* vb = video + (size_t)b * T * D;

    // ---- Phase A ----
    {
        int s0 = w * SEGW;
        float p[16];
        loadrow(vb + (size_t)min(s0, TS) * D, lane, p);

        double pn = 0.0;
#pragma unroll
        for (int j = 0; j < 16; ++j) pn += (double)p[j] * (double)p[j];
#pragma unroll
        for (int o = 32; o; o >>= 1) pn += __shfl_xor(pn, o);
        double nprev = sqrt(pn) + EPS_D;

        for (int i = 0; i < SEGW; ++i) {
            int s = s0 + i;
            int rowIdx = min(s + 1, TS);   // clamp tail loads
            float c[16];
            loadrow(vb + (size_t)rowIdx * D, lane, c);

            double cn = 0.0, dt = 0.0;
#pragma unroll
            for (int j = 0; j < 16; ++j) {
                cn += (double)c[j] * (double)c[j];
                dt += (double)c[j] * (double)p[j];
            }
#pragma unroll
            for (int o = 32; o; o >>= 1) {
                cn += __shfl_xor(cn, o);
                dt += __shfl_xor(dt, o);
            }
            double ncur = sqrt(cn) + EPS_D;
            if (lane == 0 && s < TS)
                S[s] = (float)(fabs(dt) / (nprev * ncur));
            nprev = ncur;
#pragma unroll
            for (int j = 0; j < 16; ++j) p[j] = c[j];
        }
    }
    __syncthreads();

    // ---- Phase B: rank-select ----
    // rank(e) = #{j : S[j]<S[e] || (S[j]==S[e] && j<e)}; ranks unique.
    if (tid == 0) idxs[0] = 0;
    if (tid < TS) {
        float val = S[tid];
        int rank = 0;
#pragma unroll 4
        for (int j = 0; j < TS; ++j) {
            float sj = S[j];
            rank += (sj < val) || (sj == val && j < tid);
        }
        if (rank < K) idxs[rank + 1] = tid + 1;
    }
    __syncthreads();

    // ---- Phase C: gather ----
    int grp  = tid >> 8;     // 0..3: four 256-thread groups, 4 rows in flight
    int l256 = tid & 255;
    for (int k = grp; k < KP1; k += 4) {
        int t = idxs[k];
        const float4* vs = (const float4*)(vb + (size_t)t * D);
        float4*       vd = (float4*)(out + ((size_t)b * KP1 + k) * D);
        vd[l256] = vs[l256];
    }
    const float* ab   = audio + (size_t)b * T * DA;
    float*       outA = out + (size_t)B * KP1 * D + (size_t)b * KP1 * DA;
    for (int a = tid; a < KP1 * (DA / 4); a += 1024) {
        int k = a >> 5, off = a & 31;
        int t = idxs[k];
        ((float4*)(outA + (size_t)k * DA))[off] =
            ((const float4*)(ab + (size_t)t * DA))[off];
    }
}

extern "C" void kernel_launch(void* const* d_in, const int* in_sizes, int n_in,
                              void* d_out, int out_size, void* d_ws, size_t ws_size,
                              hipStream_t stream) {
    const float* video = (const float*)d_in[0];
    const float* audio = (const float*)d_in[1];
    float* out = (float*)d_out;

    fused1_kernel<<<B, 1024, 0, stream>>>(video, audio, out);
}

// Round 13
// 49.725 us; speedup vs baseline: 5.2173x; 1.0644x over previous
//
#include <hip/hip_runtime.h>
#include <math.h>

// Problem constants (fixed by reference setup_inputs)
constexpr int B   = 128;
constexpr int T   = 300;
constexpr int D   = 1024;   // video dim
constexpr int DA  = 128;    // audio dim
constexpr int TS  = T - 1;  // 299 similarities per batch
constexpr int K   = 32;
constexpr int KP1 = K + 1;

constexpr int SEGW = 19;    // sims per wave: 16 waves * 19 = 304 >= 299

#define EPS_D 1e-5

__device__ __forceinline__ void loadrow(const float* __restrict__ row, int lane, float r[16]) {
    const float4* f = (const float4*)row;
#pragma unroll
    for (int j = 0; j < 4; ++j) {
        float4 x = f[lane + 64 * j];
        r[4 * j + 0] = x.x; r[4 * j + 1] = x.y;
        r[4 * j + 2] = x.z; r[4 * j + 3] = x.w;
    }
}

// dt = <p,c>, cn = <c,c>, each as two 8-deep f64 chains (ILP x2).
__device__ __forceinline__ void dot_norm(const float p[16], const float c[16],
                                         double& dt, double& cn) {
    double d0 = 0.0, d1 = 0.0, n0 = 0.0, n1 = 0.0;
#pragma unroll
    for (int j = 0; j < 8; ++j) {
        d0 += (double)p[j] * (double)c[j];
        n0 += (double)c[j] * (double)c[j];
    }
#pragma unroll
    for (int j = 8; j < 16; ++j) {
        d1 += (double)p[j] * (double)c[j];
        n1 += (double)c[j] * (double)c[j];
    }
    dt = d0 + d1; cn = n0 + n1;
}

// One block per batch, 1024 threads, ONE dispatch total.
// Phase A: 16 waves x 19 sims, PAIRED iterations (2 rows loaded, 2 sims
//   computed, 4 f64 butterflies batched) with 2-way-split f64 chains —
//   double the ILP of R11's proven variant; f64 precision keeps the
//   top-32 ranking exact (absmax 0.0 in 6 prior runs).
// Phase B: LDS rank-select (rank<K == top_k(-sim) stable winners).
// Phase C: gather 33 video+audio rows (L2/L3-warm from phase A).
// No atomics, no fences, no grid.sync, no workspace.
__global__ __launch_bounds__(1024) void fused2_kernel(const float* __restrict__ video,
                                                      const float* __restrict__ audio,
                                                      float* __restrict__ out) {
    __shared__ float S[TS];
    __shared__ int   idxs[KP1];

    int b    = blockIdx.x;
    int tid  = threadIdx.x;
    int w    = tid >> 6;
    int lane = tid & 63;

    const float* vb = video + (size_t)b * T * D;

    // ---- Phase A ----
    {
        int s0 = w * SEGW;
        float P[16];
        loadrow(vb + (size_t)min(s0, TS) * D, lane, P);

        double pn0 = 0.0, pn1 = 0.0;
#pragma unroll
        for (int j = 0; j < 8; ++j)  pn0 += (double)P[j] * (double)P[j];
#pragma unroll
        for (int j = 8; j < 16; ++j) pn1 += (double)P[j] * (double)P[j];
        double pn = pn0 + pn1;
#pragma unroll
        for (int o = 32; o; o >>= 1) pn += __shfl_xor(pn, o);
        double nprev = sqrt(pn) + EPS_D;

        // 9 paired iterations (18 sims) ...
#pragma unroll
        for (int i = 0; i < SEGW - 1; i += 2) {
            int s = s0 + i;
            float cB[16], cC[16];
            loadrow(vb + (size_t)min(s + 1, TS) * D, lane, cB);
            loadrow(vb + (size_t)min(s + 2, TS) * D, lane, cC);

            double dtB, cnB, dtC, cnC;
            dot_norm(P,  cB, dtB, cnB);
            dot_norm(cB, cC, dtC, cnC);
#pragma unroll
            for (int o = 32; o; o >>= 1) {
                dtB += __shfl_xor(dtB, o); cnB += __shfl_xor(cnB, o);
                dtC += __shfl_xor(dtC, o); cnC += __shfl_xor(cnC, o);
            }
            double nB = sqrt(cnB) + EPS_D;
            double nC = sqrt(cnC) + EPS_D;
            if (lane == 0) {
                if (s < TS)     S[s]     = (float)(fabs(dtB) / (nprev * nB));
                if (s + 1 < TS) S[s + 1] = (float)(fabs(dtC) / (nB * nC));
            }
            nprev = nC;
#pragma unroll
            for (int j = 0; j < 16; ++j) P[j] = cC[j];
        }
        // ... plus the odd tail sim (i = 18)
        {
            int s = s0 + (SEGW - 1);
            float cB[16];
            loadrow(vb + (size_t)min(s + 1, TS) * D, lane, cB);
            double dtB, cnB;
            dot_norm(P, cB, dtB, cnB);
#pragma unroll
            for (int o = 32; o; o >>= 1) {
                dtB += __shfl_xor(dtB, o); cnB += __shfl_xor(cnB, o);
            }
            double nB = sqrt(cnB) + EPS_D;
            if (lane == 0 && s < TS)
                S[s] = (float)(fabs(dtB) / (nprev * nB));
        }
    }
    __syncthreads();

    // ---- Phase B: rank-select ----
    // rank(e) = #{j : S[j]<S[e] || (S[j]==S[e] && j<e)}; ranks unique.
    if (tid == 0) idxs[0] = 0;
    if (tid < TS) {
        float val = S[tid];
        int rank = 0;
#pragma unroll 4
        for (int j = 0; j < TS; ++j) {
            float sj = S[j];
            rank += (sj < val) || (sj == val && j < tid);
        }
        if (rank < K) idxs[rank + 1] = tid + 1;
    }
    __syncthreads();

    // ---- Phase C: gather ----
    int grp  = tid >> 8;     // 0..3: four 256-thread groups, 4 rows in flight
    int l256 = tid & 255;
    for (int k = grp; k < KP1; k += 4) {
        int t = idxs[k];
        const float4* vs = (const float4*)(vb + (size_t)t * D);
        float4*       vd = (float4*)(out + ((size_t)b * KP1 + k) * D);
        vd[l256] = vs[l256];
    }
    const float* ab   = audio + (size_t)b * T * DA;
    float*       outA = out + (size_t)B * KP1 * D + (size_t)b * KP1 * DA;
    for (int a = tid; a < KP1 * (DA / 4); a += 1024) {
        int k = a >> 5, off = a & 31;
        int t = idxs[k];
        ((float4*)(outA + (size_t)k * DA))[off] =
            ((const float4*)(ab + (size_t)t * DA))[off];
    }
}

extern "C" void kernel_launch(void* const* d_in, const int* in_sizes, int n_in,
                              void* d_out, int out_size, void* d_ws, size_t ws_size,
                              hipStream_t stream) {
    const float* video = (const float*)d_in[0];
    const float* audio = (const float*)d_in[1];
    float* out = (float*)d_out;

    fused2_kernel<<<B, 1024, 0, stream>>>(video, audio, out);
}